// Round 2
// baseline (294.140 us; speedup 1.0000x reference)
//
#include <hip/hip_runtime.h>
#include <stdint.h>

typedef unsigned short u16;
typedef __bf16 bf16x8 __attribute__((ext_vector_type(8)));
typedef float f32x4 __attribute__((ext_vector_type(4)));

#define N_B 2
#define N_S 2048
#define N_D 1024
#define N_H 16
#define HD 64

__device__ __forceinline__ u16 f2bf(float f) {
  union { float f; uint32_t u; } v; v.f = f;
  uint32_t u = v.u + 0x7fffu + ((v.u >> 16) & 1u);
  return (u16)(u >> 16);
}

__device__ __forceinline__ void gload16(const u16* g, u16* lds) {
  __builtin_amdgcn_global_load_lds(
      (const __attribute__((address_space(1))) unsigned int*)g,
      (__attribute__((address_space(3))) unsigned int*)lds, 16, 0, 0);
}

// fp32 -> bf16 conversion (inputs are fp32 per the reference)
__global__ __launch_bounds__(256) void cvt_kernel(const float* __restrict__ src,
                                                  u16* __restrict__ dst, int n) {
  int i = (blockIdx.x * 256 + threadIdx.x) * 4;
  if (i < n) {
    float4 v = *(const float4*)(src + i);
    ushort4 o;
    o.x = f2bf(v.x); o.y = f2bf(v.y); o.z = f2bf(v.z); o.w = f2bf(v.w);
    *(ushort4*)(dst + i) = o;
  }
}

// cos/sin tables [S][32] fp32
__global__ void rope_table_kernel(float* __restrict__ cosT, float* __restrict__ sinT) {
  int t = blockIdx.x * 256 + threadIdx.x;   // 2048*32 = 65536
  int s = t >> 5, i = t & 31;
  double inv = exp(-(double)i * (9.210340371976184 / 32.0)); // 10000^(-i/32)
  double a = (double)s * inv;
  double sn, cs;
  sincos(a, &sn, &cs);
  cosT[t] = (float)cs;
  sinT[t] = (float)sn;
}

// ---------------------------------------------------------------------------
// Fused QKV projection: out = x @ W^T  (M=4096, N=1024, K=1024), bf16 MFMA.
// mode z=0: Q (+RoPE) -> Qb[bh][s][d]; z=1: K (+RoPE) -> Kb[bh][s][d];
// z=2: V -> Vtb[bh][d][s] (transposed for PV B-operand).
// LDS chunk swizzle: chunk(m,kq) stored at slot kq ^ ((m>>1)&3)  (BK=32, 4 slots)
// ---------------------------------------------------------------------------
__global__ __launch_bounds__(256) void proj_kernel(
    const u16* __restrict__ x, const u16* __restrict__ Wq,
    const u16* __restrict__ Wk, const u16* __restrict__ Wv,
    u16* __restrict__ Qb, u16* __restrict__ Kb, u16* __restrict__ Vtb,
    const float* __restrict__ cosT, const float* __restrict__ sinT)
{
  const int mode = blockIdx.z;
  const u16* Wm = (mode == 0) ? Wq : (mode == 1) ? Wk : Wv;
  const int bx = blockIdx.x, by = blockIdx.y;
  const int tid = threadIdx.x;
  const int wave = tid >> 6, lane = tid & 63;
  const int c = lane & 15, quad = lane >> 4;
  const int wm = wave & 1, wn = wave >> 1;

  __shared__ __align__(16) u16 As[128 * 32];
  __shared__ __align__(16) u16 Bs[128 * 32];

  const f32x4 zero = {0.f, 0.f, 0.f, 0.f};
  f32x4 acc[4][4];
#pragma unroll
  for (int i = 0; i < 4; ++i)
#pragma unroll
    for (int j = 0; j < 4; ++j) acc[i][j] = zero;

  for (int kt = 0; kt < 32; ++kt) {
    const int k0 = kt * 32;
    __syncthreads();
#pragma unroll
    for (int t = 0; t < 2; ++t) {
      int p = t * 256 + tid;
      int m = p >> 2, sl = p & 3;
      int kq = sl ^ ((m >> 1) & 3);
      gload16(x  + (size_t)(by * 128 + m) * N_D + k0 + kq * 8, &As[(t * 256 + wave * 64) * 8]);
      gload16(Wm + (size_t)(bx * 128 + m) * N_D + k0 + kq * 8, &Bs[(t * 256 + wave * 64) * 8]);
    }
    __syncthreads();
    bf16x8 av[4], bv[4];
#pragma unroll
    for (int i = 0; i < 4; ++i) {
      int m = wm * 64 + i * 16 + c;
      int sa = quad ^ ((m >> 1) & 3);
      av[i] = *(const bf16x8*)&As[(m * 4 + sa) * 8];
      int n = wn * 64 + i * 16 + c;
      int sb = quad ^ ((n >> 1) & 3);
      bv[i] = *(const bf16x8*)&Bs[(n * 4 + sb) * 8];
    }
#pragma unroll
    for (int i = 0; i < 4; ++i)
#pragma unroll
      for (int j = 0; j < 4; ++j)
        acc[i][j] = __builtin_amdgcn_mfma_f32_16x16x32_bf16(av[i], bv[j], acc[i][j], 0, 0, 0);
  }

  const int h = bx * 2 + wn;   // wave's 64-col span is one head
  if (mode < 2) {
    u16* Out = (mode == 0) ? Qb : Kb;
#pragma unroll
    for (int i = 0; i < 4; ++i) {
#pragma unroll
      for (int r = 0; r < 4; ++r) {
        int row = by * 128 + wm * 64 + i * 16 + quad * 4 + r;
        int b = row >> 11, s = row & 2047;
        float cs0 = cosT[s * 32 + c],      sn0 = sinT[s * 32 + c];
        float cs1 = cosT[s * 32 + 16 + c], sn1 = sinT[s * 32 + 16 + c];
        size_t base = ((size_t)(b * N_H + h) * N_S + s) * HD;
#pragma unroll
        for (int j = 0; j < 4; ++j) {
          float v = acc[i][j][r];
          float p = acc[i][j ^ 2][r];     // partner channel d +/- 32
          float cs = (j & 1) ? cs1 : cs0;
          float sn = (j & 1) ? sn1 : sn0;
          float res = (j < 2) ? (v * cs - p * sn) : (v * cs + p * sn);
          Out[base + j * 16 + c] = f2bf(res);
        }
      }
    }
  } else {
#pragma unroll
    for (int i = 0; i < 4; ++i) {
      int srow = by * 128 + wm * 64 + i * 16 + quad * 4;
      int b = srow >> 11, sb = srow & 2047;
#pragma unroll
      for (int j = 0; j < 4; ++j) {
        int d = j * 16 + c;
        ushort4 pk;
        pk.x = f2bf(acc[i][j][0]);
        pk.y = f2bf(acc[i][j][1]);
        pk.z = f2bf(acc[i][j][2]);
        pk.w = f2bf(acc[i][j][3]);
        *(ushort4*)&Vtb[((size_t)(b * N_H + h) * HD + d) * N_S + sb] = pk;
      }
    }
  }
}

// ---------------------------------------------------------------------------
// Flash-style causal attention. Computes S^T = K*Q^T per k-tile so softmax
// stats are mostly in-lane and P^T writes to LDS are 8B-contiguous.
// Block: 128 q-rows (4 waves x 32), iterates k-tiles 0..qt.
// Q fragments kept in registers (loaded once from global). LDS = 64 KB.
// ---------------------------------------------------------------------------
__global__ __launch_bounds__(256) void attn_kernel(
    const u16* __restrict__ Qb, const u16* __restrict__ Kb,
    const u16* __restrict__ Vtb, u16* __restrict__ Ab)
{
  const int qt = blockIdx.x;   // 0..15
  const int bh = blockIdx.y;   // 0..31
  const int tid = threadIdx.x;
  const int wave = tid >> 6, lane = tid & 63;
  const int c = lane & 15, quad = lane >> 4;

  __shared__ __align__(16) u16 Ks[128 * 64];      // chunk(m,kq) at slot kq^(m&7)
  __shared__ __align__(16) u16 Vs[64 * 128];      // chunk(d,kq) at slot kq^(d&15)
  __shared__ __align__(16) u16 Ps[4][32 * 128];   // per-wave P [q][s_k], 16B chunks swizzled by q&15

  const u16* Qg = Qb + ((size_t)bh * N_S + qt * 128) * HD;
  const u16* Kg = Kb + (size_t)bh * N_S * HD;
  const u16* Vg = Vtb + (size_t)bh * HD * N_S;

  // Q fragments in registers: qreg[ks][jQ] = Q[q=wave*32+jQ*16+c][d=(ks*4+quad)*8 ..+7]
  bf16x8 qreg[2][2];
#pragma unroll
  for (int ks = 0; ks < 2; ++ks)
#pragma unroll
    for (int jQ = 0; jQ < 2; ++jQ) {
      int q = wave * 32 + jQ * 16 + c;
      qreg[ks][jQ] = *(const bf16x8*)(Qg + q * HD + (ks * 4 + quad) * 8);
    }

  const f32x4 zero = {0.f, 0.f, 0.f, 0.f};
  f32x4 acc_o[2][4];
#pragma unroll
  for (int mt = 0; mt < 2; ++mt)
#pragma unroll
    for (int nt = 0; nt < 4; ++nt) acc_o[mt][nt] = zero;

  float mrow[2] = {-1e30f, -1e30f};
  float lrow[2] = {0.f, 0.f};
  const float CLOG = 0.18033688011112042f;   // log2(e)/8  (folds the 1/sqrt(64) scale)
  u16* Pw = &Ps[wave][0];

  for (int kt = 0; kt <= qt; ++kt) {
    __syncthreads();   // protect K/V LDS from prior reads; drains all staging
#pragma unroll
    for (int t = 0; t < 4; ++t) {
      int p = t * 256 + tid;
      int m = p >> 3, sl = p & 7;
      int kq = sl ^ (m & 7);
      gload16(Kg + (size_t)(kt * 128 + m) * HD + kq * 8, &Ks[(t * 256 + wave * 64) * 8]);
      int d = p >> 4, sl2 = p & 15;
      int kq2 = sl2 ^ (d & 15);
      gload16(Vg + (size_t)d * N_S + kt * 128 + kq2 * 8, &Vs[(t * 256 + wave * 64) * 8]);
    }
    __syncthreads();

    // S^T = K * Q^T : acc_s[iK][jQ], rows s_k = iK*16+quad*4+r, cols q = jQ*16+c
    f32x4 acc_s[8][2];
#pragma unroll
    for (int iK = 0; iK < 8; ++iK)
#pragma unroll
      for (int jQ = 0; jQ < 2; ++jQ) acc_s[iK][jQ] = zero;
#pragma unroll
    for (int ks = 0; ks < 2; ++ks) {
      bf16x8 kf[8];
      int kq = ks * 4 + quad;
#pragma unroll
      for (int iK = 0; iK < 8; ++iK) {
        int m = iK * 16 + c;
        kf[iK] = *(const bf16x8*)&Ks[(m * 8 + (kq ^ (m & 7))) * 8];
      }
#pragma unroll
      for (int iK = 0; iK < 8; ++iK)
#pragma unroll
        for (int jQ = 0; jQ < 2; ++jQ)
          acc_s[iK][jQ] = __builtin_amdgcn_mfma_f32_16x16x32_bf16(kf[iK], qreg[ks][jQ], acc_s[iK][jQ], 0, 0, 0);
    }

    if (kt == qt) {   // causal mask on diagonal tile
#pragma unroll
      for (int iK = 0; iK < 8; ++iK)
#pragma unroll
        for (int jQ = 0; jQ < 2; ++jQ)
#pragma unroll
          for (int r = 0; r < 4; ++r) {
            int sk = iK * 16 + quad * 4 + r;
            int q  = wave * 32 + jQ * 16 + c;
            if (sk > q) acc_s[iK][jQ][r] = -1e30f;
          }
    }

    // online softmax update (per q-column of S^T, stats in-lane + 2 shuffles)
    float alpha[2];
#pragma unroll
    for (int jQ = 0; jQ < 2; ++jQ) {
      float mx = -1e30f;
#pragma unroll
      for (int iK = 0; iK < 8; ++iK)
#pragma unroll
        for (int r = 0; r < 4; ++r) mx = fmaxf(mx, acc_s[iK][jQ][r]);
      mx = fmaxf(mx, __shfl_xor(mx, 16, 64));
      mx = fmaxf(mx, __shfl_xor(mx, 32, 64));
      float mnew = fmaxf(mrow[jQ], mx);
      alpha[jQ] = exp2f((mrow[jQ] - mnew) * CLOG);
      mrow[jQ] = mnew;
      float ls = 0.f;
#pragma unroll
      for (int iK = 0; iK < 8; ++iK)
#pragma unroll
        for (int r = 0; r < 4; ++r) {
          float p = exp2f((acc_s[iK][jQ][r] - mnew) * CLOG);
          acc_s[iK][jQ][r] = p;
          ls += p;
        }
      ls += __shfl_xor(ls, 16, 64);
      ls += __shfl_xor(ls, 32, 64);
      lrow[jQ] = lrow[jQ] * alpha[jQ] + ls;
    }

    // write P (bf16) to own wave's LDS region, 8B chunks, 16B-granular swizzle
#pragma unroll
    for (int iK = 0; iK < 8; ++iK)
#pragma unroll
      for (int jQ = 0; jQ < 2; ++jQ) {
        int q = jQ * 16 + c;
        int ck = iK * 2 + (quad >> 1);
        int swz = ck ^ (q & 15);
        ushort4 pk;
        pk.x = f2bf(acc_s[iK][jQ][0]);
        pk.y = f2bf(acc_s[iK][jQ][1]);
        pk.z = f2bf(acc_s[iK][jQ][2]);
        pk.w = f2bf(acc_s[iK][jQ][3]);
        *(ushort4*)&Pw[q * 128 + swz * 8 + (quad & 1) * 4] = pk;
      }

    // rescale O accumulator (alpha per row q = mt*16+quad*4+r via shuffle)
#pragma unroll
    for (int mt = 0; mt < 2; ++mt) {
      float a0 = __shfl(alpha[mt], quad * 4 + 0, 64);
      float a1 = __shfl(alpha[mt], quad * 4 + 1, 64);
      float a2 = __shfl(alpha[mt], quad * 4 + 2, 64);
      float a3 = __shfl(alpha[mt], quad * 4 + 3, 64);
#pragma unroll
      for (int nt = 0; nt < 4; ++nt) {
        acc_o[mt][nt][0] *= a0;
        acc_o[mt][nt][1] *= a1;
        acc_o[mt][nt][2] *= a2;
        acc_o[mt][nt][3] *= a3;
      }
    }

    // O += P @ V
#pragma unroll
    for (int ks = 0; ks < 4; ++ks) {
      bf16x8 pf[2], vf[4];
      int kq = ks * 4 + quad;
#pragma unroll
      for (int mt = 0; mt < 2; ++mt) {
        int q = mt * 16 + c;
        int swz = kq ^ (q & 15);
        pf[mt] = *(const bf16x8*)&Pw[q * 128 + swz * 8];
      }
#pragma unroll
      for (int nt = 0; nt < 4; ++nt) {
        int d = nt * 16 + c;
        vf[nt] = *(const bf16x8*)&Vs[(d * 16 + (kq ^ (d & 15))) * 8];
      }
#pragma unroll
      for (int mt = 0; mt < 2; ++mt)
#pragma unroll
        for (int nt = 0; nt < 4; ++nt)
          acc_o[mt][nt] = __builtin_amdgcn_mfma_f32_16x16x32_bf16(pf[mt], vf[nt], acc_o[mt][nt], 0, 0, 0);
    }
  }

  // normalize + store to Ab[b][s][h*64+d]
  const int b = bh >> 4, h = bh & 15;
#pragma unroll
  for (int mt = 0; mt < 2; ++mt) {
    float l0 = __shfl(lrow[mt], quad * 4 + 0, 64);
    float l1 = __shfl(lrow[mt], quad * 4 + 1, 64);
    float l2 = __shfl(lrow[mt], quad * 4 + 2, 64);
    float l3 = __shfl(lrow[mt], quad * 4 + 3, 64);
    float inv[4] = {1.f / l0, 1.f / l1, 1.f / l2, 1.f / l3};
#pragma unroll
    for (int nt = 0; nt < 4; ++nt) {
      int d = nt * 16 + c;
#pragma unroll
      for (int r = 0; r < 4; ++r) {
        int q = qt * 128 + wave * 32 + mt * 16 + quad * 4 + r;
        Ab[((size_t)(b * N_S + q)) * N_D + h * HD + d] = f2bf(acc_o[mt][nt][r] * inv[r]);
      }
    }
  }
}

// ---------------------------------------------------------------------------
// out = attn_out @ Wo^T, fp32 store to d_out
// ---------------------------------------------------------------------------
__global__ __launch_bounds__(256) void out_gemm_kernel(
    const u16* __restrict__ A, const u16* __restrict__ Wo, float* __restrict__ out)
{
  const int bx = blockIdx.x, by = blockIdx.y;
  const int tid = threadIdx.x;
  const int wave = tid >> 6, lane = tid & 63;
  const int c = lane & 15, quad = lane >> 4;
  const int wm = wave & 1, wn = wave >> 1;

  __shared__ __align__(16) u16 As[128 * 32];
  __shared__ __align__(16) u16 Bs[128 * 32];

  const f32x4 zero = {0.f, 0.f, 0.f, 0.f};
  f32x4 acc[4][4];
#pragma unroll
  for (int i = 0; i < 4; ++i)
#pragma unroll
    for (int j = 0; j < 4; ++j) acc[i][j] = zero;

  for (int kt = 0; kt < 32; ++kt) {
    const int k0 = kt * 32;
    __syncthreads();
#pragma unroll
    for (int t = 0; t < 2; ++t) {
      int p = t * 256 + tid;
      int m = p >> 2, sl = p & 3;
      int kq = sl ^ ((m >> 1) & 3);
      gload16(A  + (size_t)(by * 128 + m) * N_D + k0 + kq * 8, &As[(t * 256 + wave * 64) * 8]);
      gload16(Wo + (size_t)(bx * 128 + m) * N_D + k0 + kq * 8, &Bs[(t * 256 + wave * 64) * 8]);
    }
    __syncthreads();
    bf16x8 av[4], bv[4];
#pragma unroll
    for (int i = 0; i < 4; ++i) {
      int m = wm * 64 + i * 16 + c;
      int sa = quad ^ ((m >> 1) & 3);
      av[i] = *(const bf16x8*)&As[(m * 4 + sa) * 8];
      int n = wn * 64 + i * 16 + c;
      int sb = quad ^ ((n >> 1) & 3);
      bv[i] = *(const bf16x8*)&Bs[(n * 4 + sb) * 8];
    }
#pragma unroll
    for (int i = 0; i < 4; ++i)
#pragma unroll
      for (int j = 0; j < 4; ++j)
        acc[i][j] = __builtin_amdgcn_mfma_f32_16x16x32_bf16(av[i], bv[j], acc[i][j], 0, 0, 0);
  }

#pragma unroll
  for (int i = 0; i < 4; ++i)
#pragma unroll
    for (int r = 0; r < 4; ++r) {
      int row = by * 128 + wm * 64 + i * 16 + quad * 4 + r;
#pragma unroll
      for (int j = 0; j < 4; ++j) {
        int col = bx * 128 + wn * 64 + j * 16 + c;
        out[(size_t)row * N_D + col] = acc[i][j][r];
      }
    }
}

extern "C" void kernel_launch(void* const* d_in, const int* in_sizes, int n_in,
                              void* d_out, int out_size, void* d_ws, size_t ws_size,
                              hipStream_t stream) {
  const float* x  = (const float*)d_in[0];
  const float* Wq = (const float*)d_in[1];
  const float* Wk = (const float*)d_in[2];
  const float* Wv = (const float*)d_in[3];
  const float* Wo = (const float*)d_in[4];
  // d_in[5] = causal mask: deterministic, hardcoded in attn_kernel.
  float* out = (float*)d_out;
  char* ws = (char*)d_ws;
  u16* xb   = (u16*)(ws);                               // [4096][1024] bf16, 8 MB
  u16* Wqb  = (u16*)(ws + ( 8u << 20));                 // 2 MB
  u16* Wkb  = (u16*)(ws + (10u << 20));                 // 2 MB
  u16* Wvb  = (u16*)(ws + (12u << 20));                 // 2 MB
  u16* Wob  = (u16*)(ws + (14u << 20));                 // 2 MB
  u16* Qb   = (u16*)(ws + (16u << 20));                 // [32][2048][64] bf16, 8 MB
  u16* Kb   = (u16*)(ws + (24u << 20));                 // 8 MB
  u16* Vtb  = (u16*)(ws + (32u << 20));                 // [32][64][2048] bf16, 8 MB
  u16* Ab   = (u16*)(ws + (40u << 20));                 // [4096][1024] bf16, 8 MB
  float* cosT = (float*)(ws + (48u << 20));             // [2048][32] fp32
  float* sinT = (float*)(ws + (48u << 20) + (1u << 20));

  const int NX = N_B * N_S * N_D;   // 4194304
  const int NW = N_D * N_D;         // 1048576
  cvt_kernel<<<NX / 1024, 256, 0, stream>>>(x, xb, NX);
  cvt_kernel<<<NW / 1024, 256, 0, stream>>>(Wq, Wqb, NW);
  cvt_kernel<<<NW / 1024, 256, 0, stream>>>(Wk, Wkb, NW);
  cvt_kernel<<<NW / 1024, 256, 0, stream>>>(Wv, Wvb, NW);
  cvt_kernel<<<NW / 1024, 256, 0, stream>>>(Wo, Wob, NW);
  rope_table_kernel<<<256, 256, 0, stream>>>(cosT, sinT);
  proj_kernel<<<dim3(8, 32, 3), 256, 0, stream>>>(xb, Wqb, Wkb, Wvb, Qb, Kb, Vtb, cosT, sinT);
  attn_kernel<<<dim3(16, 32), 256, 0, stream>>>(Qb, Kb, Vtb, Ab);
  out_gemm_kernel<<<dim3(8, 32), 256, 0, stream>>>(Ab, Wob, out);
}